// Round 1
// baseline (64.380 us; speedup 1.0000x reference)
//
#include <hip/hip_runtime.h>
#include <math.h>

// QuantumKernel: 22-wire RY layer + 1 ring of CNOTs for x and y, then
// out(b,i,j) = | sum_k psi_y[b,i,k] * psi_x[b,k,j] |  (states are real).
//
// Closed form: RY layer gives product state amp(a) = prod_w f_w(a_w),
// f_w(0)=cos(t_w/2), f_w(1)=sin(t_w/2). The sequential CNOT ring is a basis
// permutation s_k = prefix_xor(a)_k (k>=1), s_0 = a_1^...^a_21; inverse:
//   a_0 = s_0^s_21, a_1 = s_1^s_0^s_21, a_k = s_k^s_{k-1} (k=2..21).
// Wire w <-> bit (21-w) of the flat index. Only a_0,a_1,a_20,a_21 depend on
// the two contracted wires (20,21), so per batch b (wires 0..19) we compute
// an 18-factor core product once and 4 corner factors per amplitude.

#define N_WIRES 22

__global__ __launch_bounds__(256) void quantum_overlap_kernel(
    const float* __restrict__ x, const float* __restrict__ y,
    float* __restrict__ out)
{
    // f tables: fx[2*w + bit] = (bit ? sin : cos)(x[w]/2), same for y.
    __shared__ float fx[2 * N_WIRES];
    __shared__ float fy[2 * N_WIRES];
    const int t = threadIdx.x;
    if (t < N_WIRES) {
        float sv, cv;
        sincosf(0.5f * x[t], &sv, &cv);
        fx[2 * t] = cv; fx[2 * t + 1] = sv;
        sincosf(0.5f * y[t], &sv, &cv);
        fy[2 * t] = cv; fy[2 * t + 1] = sv;
    }
    __syncthreads();

    const unsigned b = blockIdx.x * 256u + (unsigned)t;  // wires 0..19; wire w = bit (19-w)

    // core = prod_{k=2..19} f_k(s_k ^ s_{k-1})
    float coreX = 1.0f, coreY = 1.0f;
#pragma unroll
    for (int k = 2; k <= 19; ++k) {
        unsigned bit = ((b >> (19 - k)) ^ (b >> (20 - k))) & 1u;
        coreX *= fx[2 * k + bit];
        coreY *= fy[2 * k + bit];
    }

    const unsigned s0  = (b >> 19) & 1u;
    const unsigned s1  = (b >> 18) & 1u;
    const unsigned s19 = b & 1u;

    // Amplitudes for the four (s20, s21) corners.
    float X[2][2], Y[2][2];  // [w20][w21]
#pragma unroll
    for (int i20 = 0; i20 < 2; ++i20) {
#pragma unroll
        for (int i21 = 0; i21 < 2; ++i21) {
            unsigned a0  = s0 ^ (unsigned)i21;
            unsigned a1  = s1 ^ s0 ^ (unsigned)i21;
            unsigned a20 = (unsigned)i20 ^ s19;
            unsigned a21 = (unsigned)i21 ^ (unsigned)i20;
            float gX = fx[a0] * fx[2 + a1] * fx[40 + a20] * fx[42 + a21];
            float gY = fy[a0] * fy[2 + a1] * fy[40 + a20] * fy[42 + a21];
            X[i20][i21] = coreX * gX;
            Y[i20][i21] = coreY * gY;
        }
    }

    // out(b,i,j) = | Y[i][0]*X[0][j] + Y[i][1]*X[1][j] |, idx = 4b + 2i + j
    float4 o;
    o.x = fabsf(Y[0][0] * X[0][0] + Y[0][1] * X[1][0]);
    o.y = fabsf(Y[0][0] * X[0][1] + Y[0][1] * X[1][1]);
    o.z = fabsf(Y[1][0] * X[0][0] + Y[1][1] * X[1][0]);
    o.w = fabsf(Y[1][0] * X[0][1] + Y[1][1] * X[1][1]);
    reinterpret_cast<float4*>(out)[b] = o;
}

extern "C" void kernel_launch(void* const* d_in, const int* in_sizes, int n_in,
                              void* d_out, int out_size, void* d_ws, size_t ws_size,
                              hipStream_t stream) {
    const float* x = (const float*)d_in[0];
    const float* y = (const float*)d_in[1];
    float* out = (float*)d_out;
    // out_size = 2^22; one thread per batch index b in [0, 2^20)
    const unsigned n_b = 1u << 20;
    quantum_overlap_kernel<<<n_b / 256, 256, 0, stream>>>(x, y, out);
}

// Round 2
// 63.953 us; speedup vs baseline: 1.0067x; 1.0067x over previous
//
#include <hip/hip_runtime.h>
#include <math.h>

// QuantumKernel closed form (see R0 notes):
//   amplitude(s) = prod_w f_w(a_w(s)), f_w(0)=cos(t_w/2), f_w(1)=sin(t_w/2),
//   a_0=s0^s21, a_1=s1^s0^s21, a_k=s_k^s_{k-1} (k=2..21)  [CNOT-ring inverse]
//   out(b,i,j) = |coreX*coreY| * |M[s0,s1,s19][i][j]|
// where core bits are c_k = s_k^s_{k-1} = bits of g = b^(b>>1):
//   g bit p = c_{19-p} (p=0..17)  ->  idx2 = g&511 covers k=19..11,
//                                     idx1 = (g>>9)&511 covers k=10..2.
// R0 was LDS-bound (~50 ds_read/thread). Here: precompute 4x512 core-product
// tables + 8x float4 |M| table into d_ws (8.3 KB, L1/L2-resident), main
// kernel = 4 cached loads + float4 load + 6 mults + float4 store (store-bound).

__global__ __launch_bounds__(256) void qk_precompute(
    const float* __restrict__ x, const float* __restrict__ y,
    float* __restrict__ ws)
{
    __shared__ float f[2][44];   // f[0][2w+bit] for x, f[1] for y
    const int t = threadIdx.x;
    if (t < 22) {
        float sv, cv;
        sincosf(0.5f * x[t], &sv, &cv);
        f[0][2 * t] = cv; f[0][2 * t + 1] = sv;
        sincosf(0.5f * y[t], &sv, &cv);
        f[1][2 * t] = cv; f[1][2 * t + 1] = sv;
    }
    __syncthreads();

    // ws layout: [0:512)=T1x, [512:1024)=T1y, [1024:1536)=T2x, [1536:2048)=T2y,
    //            [2048:2080)=absM (8 x float4 over (i,j)).
    const int e   = blockIdx.x * 256 + t;   // 0..2047 with grid=8
    const int tbl = e >> 9;                 // 0:T1x 1:T1y 2:T2x 3:T2y (block-uniform)
    const int i   = e & 511;
    const float* F = f[tbl & 1];
    float prod = 1.0f;
    if (tbl < 2) {
#pragma unroll
        for (int q = 0; q < 9; ++q) prod *= F[2 * (10 - q) + ((i >> q) & 1)];
    } else {
#pragma unroll
        for (int p = 0; p < 9; ++p) prod *= F[2 * (19 - p) + ((i >> p) & 1)];
    }
    ws[e] = prod;

    if (blockIdx.x == 0 && t < 8) {
        const int s0 = (t >> 2) & 1, s1 = (t >> 1) & 1, s19 = t & 1;
#pragma unroll
        for (int ii = 0; ii < 2; ++ii) {
#pragma unroll
            for (int j = 0; j < 2; ++j) {
                float sum = 0.0f;
#pragma unroll
                for (int k = 0; k < 2; ++k) {
                    // X corner: s20=k, s21=j ; Y corner: s20=ii, s21=k
                    float kx = f[0][s0 ^ j] * f[0][2 + (s1 ^ s0 ^ j)]
                             * f[0][40 + (k ^ s19)] * f[0][42 + (j ^ k)];
                    float ky = f[1][s0 ^ k] * f[1][2 + (s1 ^ s0 ^ k)]
                             * f[1][40 + (ii ^ s19)] * f[1][42 + (k ^ ii)];
                    sum += ky * kx;
                }
                ws[2048 + 4 * t + 2 * ii + j] = fabsf(sum);
            }
        }
    }
}

__global__ __launch_bounds__(256) void qk_main(
    const float* __restrict__ ws, float* __restrict__ out)
{
    const unsigned b  = blockIdx.x * 256u + threadIdx.x;   // wires 0..19
    const unsigned g  = b ^ (b >> 1);
    const unsigned i2 = g & 511u;           // core k=11..19 (per-lane, coalesced perm)
    const unsigned i1 = (g >> 9) & 511u;    // core k=2..10  (wave-uniform)
    const float coreX = ws[i1]        * ws[1024u + i2];
    const float coreY = ws[512u + i1] * ws[1536u + i2];
    const float p = fabsf(coreX * coreY);
    const unsigned m = ((b >> 17) & 6u) | (b & 1u);   // s0<<2 | s1<<1 | s19
    const float4 a = reinterpret_cast<const float4*>(ws + 2048)[m];
    float4 o;
    o.x = p * a.x; o.y = p * a.y; o.z = p * a.z; o.w = p * a.w;
    reinterpret_cast<float4*>(out)[b] = o;
}

extern "C" void kernel_launch(void* const* d_in, const int* in_sizes, int n_in,
                              void* d_out, int out_size, void* d_ws, size_t ws_size,
                              hipStream_t stream) {
    const float* x = (const float*)d_in[0];
    const float* y = (const float*)d_in[1];
    float* ws  = (float*)d_ws;   // needs 2080 floats = 8320 B
    float* out = (float*)d_out;  // 2^22 floats
    qk_precompute<<<8, 256, 0, stream>>>(x, y, ws);
    const unsigned n_b = 1u << 20;           // one thread per batch index b
    qk_main<<<n_b / 256, 256, 0, stream>>>(ws, out);
}

// Round 3
// 61.982 us; speedup vs baseline: 1.0387x; 1.0318x over previous
//
#include <hip/hip_runtime.h>
#include <math.h>

// QuantumKernel closed form (derivation in R0/R1 notes):
//   amplitude(s) = prod_w f_w(a_w(s)), f_w(0)=cos(t/2), f_w(1)=sin(t/2);
//   CNOT-ring inverse: a_0=s0^s21, a_1=s1^s0^s21, a_k=s_k^s_{k-1} (k=2..21).
//   out(b,i,j) = U1[(g>>9)&511] * U2[g&511] * absM[s0,s1,s19][i][j],
//   g = b^(b>>1)  (core bits c_k = g bit (19-k), k=2..19),
//   U1[i] = |prod_{q=0..8} (fx*fy)[2*(10-q)+bit_q(i)]|   (wires 2..10),
//   U2[i] = |prod_{p=0..8} (fx*fy)[2*(19-p)+bit_p(i)]|   (wires 11..19),
//   absM[m][i][j] = |sum_k Ycorner(i,k)*Xcorner(k,j)|    (wires 0,1,20,21).
// Single fused kernel: per-block LDS tables (amortized over 4 float4 stores
// per thread), hot loop = 3 LDS reads + ~10 VALU + 1 coalesced float4 store.
// Store-bound floor: 16.8 MB / 6.3 TB/s ~= 2.7 us.

#define BLOCKS 1024
#define QPT 4   // float4 outputs per thread; 1024*256*4 = 2^20

__global__ __launch_bounds__(256) void qk_fused(
    const float* __restrict__ x, const float* __restrict__ y,
    float* __restrict__ out)
{
    __shared__ float fx[44], fy[44], h[44];
    __shared__ float U1[512], U2[512];
    __shared__ float absM[32];
    const int t = threadIdx.x;

    if (t < 22) {
        float sv, cv;
        sincosf(0.5f * x[t], &sv, &cv);
        fx[2 * t] = cv; fx[2 * t + 1] = sv;
        sincosf(0.5f * y[t], &sv, &cv);
        fy[2 * t] = cv; fy[2 * t + 1] = sv;
    }
    __syncthreads();
    if (t < 44) h[t] = fx[t] * fy[t];
    __syncthreads();

#pragma unroll
    for (int r = 0; r < 2; ++r) {
        const int i = t + 256 * r;
        float p1 = 1.0f, p2 = 1.0f;
#pragma unroll
        for (int q = 0; q < 9; ++q) {
            const int bit = (i >> q) & 1;
            p1 *= h[2 * (10 - q) + bit];
            p2 *= h[2 * (19 - q) + bit];
        }
        U1[i] = fabsf(p1);
        U2[i] = fabsf(p2);
    }
    if (t < 8) {
        const int s0 = (t >> 2) & 1, s1 = (t >> 1) & 1, s19 = t & 1;
#pragma unroll
        for (int ii = 0; ii < 2; ++ii) {
#pragma unroll
            for (int j = 0; j < 2; ++j) {
                float sum = 0.0f;
#pragma unroll
                for (int k = 0; k < 2; ++k) {
                    // X corner: s20=k, s21=j ; Y corner: s20=ii, s21=k
                    float kx = fx[s0 ^ j] * fx[2 + (s1 ^ s0 ^ j)]
                             * fx[40 + (k ^ s19)] * fx[42 + (j ^ k)];
                    float ky = fy[s0 ^ k] * fy[2 + (s1 ^ s0 ^ k)]
                             * fy[40 + (ii ^ s19)] * fy[42 + (k ^ ii)];
                    sum += ky * kx;
                }
                absM[4 * t + 2 * ii + j] = fabsf(sum);
            }
        }
    }
    __syncthreads();

    const unsigned base = blockIdx.x * (256u * QPT);
#pragma unroll
    for (int k = 0; k < QPT; ++k) {
        const unsigned b = base + k * 256u + (unsigned)t;  // batch index, wires 0..19
        const unsigned g = b ^ (b >> 1);
        // U1: wave-broadcast read; U2: 64 consecutive dwords permuted (2 lanes/bank)
        const float p = U1[(g >> 9) & 511u] * U2[g & 511u];
        const unsigned m = ((b >> 17) & 6u) | (b & 1u);    // s0<<2 | s1<<1 | s19
        const float4 a = reinterpret_cast<const float4*>(absM)[m];
        float4 o;
        o.x = p * a.x; o.y = p * a.y; o.z = p * a.z; o.w = p * a.w;
        reinterpret_cast<float4*>(out)[b] = o;
    }
}

extern "C" void kernel_launch(void* const* d_in, const int* in_sizes, int n_in,
                              void* d_out, int out_size, void* d_ws, size_t ws_size,
                              hipStream_t stream) {
    const float* x = (const float*)d_in[0];
    const float* y = (const float*)d_in[1];
    float* out = (float*)d_out;   // 2^22 floats
    qk_fused<<<BLOCKS, 256, 0, stream>>>(x, y, out);
}